// Round 13
// baseline (584.961 us; speedup 1.0000x reference)
//
#include <hip/hip_runtime.h>
#include <math.h>

#define HD 128
#define PB 256   // partition blocks for bucketed CSR build
#define SCB 4096 // elements per block in multi-block scan

typedef __attribute__((ext_vector_type(8))) short short8;
typedef __attribute__((ext_vector_type(4))) float f32x4;

__device__ __forceinline__ float sigf(float v) { return 1.0f / (1.0f + __expf(-v)); }

__device__ __forceinline__ unsigned short f2bf(float f) {
  union { float f; unsigned u; } v; v.f = f;
  unsigned r = (v.u + 0x7fffu + ((v.u >> 16) & 1u)) >> 16;
  return (unsigned short)r;
}
__device__ __forceinline__ float bf2f(unsigned short b) {
  union { unsigned u; float f; } v; v.u = ((unsigned)b) << 16;
  return v.f;
}

// ---------------- CSR build ----------------

__global__ __launch_bounds__(256) void bcount_k(const int* __restrict__ ei,
                                                int* __restrict__ bcnt,
                                                int E, int N, int shift, int NB) {
  __shared__ int h[256];
  const int blk = blockIdx.x, tid = threadIdx.x;
  h[tid] = 0;
  __syncthreads();
  int per = (E + PB - 1) / PB;
  int lo = blk * per;
  int hi = (lo + per < E) ? lo + per : E;
  for (int e = lo + tid; e < hi; e += 256) {
    int d = ei[(size_t)E + e];
    if ((unsigned)d >= (unsigned)N) continue;
    atomicAdd(&h[d >> shift], 1);
  }
  __syncthreads();
  if (tid < NB) bcnt[tid * PB + blk] = h[tid];
}

__global__ __launch_bounds__(256) void scan1_k(const int* __restrict__ a,
                                               int* __restrict__ bsums, int total) {
  __shared__ int ts[256];
  int b = blockIdx.x, tid = threadIdx.x;
  int lo = b * SCB + tid * 16;
  int s = 0;
#pragma unroll
  for (int i = 0; i < 16; ++i) {
    int idx = lo + i;
    if (idx < total) s += a[idx];
  }
  ts[tid] = s;
  __syncthreads();
  for (int off = 128; off > 0; off >>= 1) {
    if (tid < off) ts[tid] += ts[tid + off];
    __syncthreads();
  }
  if (tid == 0) bsums[b] = ts[0];
}

__global__ __launch_bounds__(256) void scan2_k(int* __restrict__ bsums, int nb) {
  __shared__ int ts[256];
  int tid = threadIdx.x;
  int v = (tid < nb) ? bsums[tid] : 0;
  ts[tid] = v;
  __syncthreads();
  for (int off = 1; off < 256; off <<= 1) {
    int u = (tid >= off) ? ts[tid - off] : 0;
    __syncthreads();
    ts[tid] += u;
    __syncthreads();
  }
  if (tid < nb) bsums[tid] = ts[tid] - v;  // exclusive
}

__global__ __launch_bounds__(256) void scan3_k(int* __restrict__ a,
                                               const int* __restrict__ bsums,
                                               int total, int nblk) {
  __shared__ int ts[256];
  int b = blockIdx.x, tid = threadIdx.x;
  int lo = b * SCB + tid * 16;
  int pre[16];
  int s = 0;
#pragma unroll
  for (int i = 0; i < 16; ++i) {
    int idx = lo + i;
    int xv = (idx < total) ? a[idx] : 0;
    pre[i] = s;
    s += xv;
  }
  ts[tid] = s;
  __syncthreads();
  for (int off = 1; off < 256; off <<= 1) {
    int u = (tid >= off) ? ts[tid - off] : 0;
    __syncthreads();
    ts[tid] += u;
    __syncthreads();
  }
  int off0 = ts[tid] - s + bsums[b];
#pragma unroll
  for (int i = 0; i < 16; ++i) {
    int idx = lo + i;
    if (idx < total) a[idx] = off0 + pre[i];
  }
  if (b == nblk - 1 && tid == 255) a[total] = off0 + s;  // grand total
}

__global__ __launch_bounds__(256) void bpart_k(const int* __restrict__ ei,
                                               const int* __restrict__ bstart,
                                               unsigned* __restrict__ ebuf,
                                               int E, int N, int shift, int NB,
                                               int sbits) {
  __shared__ int cur[256];
  const int blk = blockIdx.x, tid = threadIdx.x;
  if (tid < NB) cur[tid] = bstart[tid * PB + blk];
  __syncthreads();
  int per = (E + PB - 1) / PB;
  int lo = blk * per;
  int hi = (lo + per < E) ? lo + per : E;
  const unsigned dmask = (1u << shift) - 1u;
  for (int e = lo + tid; e < hi; e += 256) {
    int s = ei[e];
    int d = ei[(size_t)E + e];
    if ((unsigned)s >= (unsigned)N || (unsigned)d >= (unsigned)N) continue;
    int p = atomicAdd(&cur[d >> shift], 1);
    ebuf[p] = (((unsigned)d & dmask) << sbits) | (unsigned)s;
  }
}

__global__ __launch_bounds__(256) void bfill2_k(const unsigned* __restrict__ ebuf,
                                                const int* __restrict__ bstart,
                                                int* __restrict__ rowstart,
                                                int* __restrict__ csr,
                                                int N, int shift, int NB, int sbits) {
  __shared__ int cnt[2048];
  __shared__ int tsum[256];
  const int b = blockIdx.x, tid = threadIdx.x;
  const int d0 = b << shift;
  int dmax = d0 + (1 << shift);
  if (dmax > N) dmax = N;
  const int nd = dmax - d0;
  const unsigned smask = (1u << sbits) - 1u;
  for (int i = tid; i < nd; i += 256) cnt[i] = 0;
  __syncthreads();
  const int base = bstart[b * PB];
  const int end = bstart[(b + 1) * PB];  // b=NB-1 -> bstart[NB*PB] = grand total
  for (int idx = base + tid; idx < end; idx += 256)
    atomicAdd(&cnt[ebuf[idx] >> sbits], 1);
  __syncthreads();
  const int C = (nd + 255) / 256;  // <= 8
  int lo = tid * C;
  int hi = (lo + C < nd) ? lo + C : nd;
  int loc[8];
  int s = 0;
  for (int i = lo; i < hi; ++i) {
    loc[i - lo] = cnt[i];
    s += cnt[i];
  }
  tsum[tid] = s;
  __syncthreads();
  for (int off = 1; off < 256; off <<= 1) {
    int u = (tid >= off) ? tsum[tid - off] : 0;
    __syncthreads();
    tsum[tid] += u;
    __syncthreads();
  }
  int run = tsum[tid] - s + base;
  for (int i = lo; i < hi; ++i) {
    rowstart[d0 + i] = run;
    cnt[i] = run;  // becomes the cursor
    run += loc[i - lo];
  }
  if (b == NB - 1 && tid == 255) rowstart[N] = end;
  __syncthreads();
  for (int idx = base + tid; idx < end; idx += 256) {
    unsigned pk = ebuf[idx];
    int p = atomicAdd(&cnt[pk >> sbits], 1);
    csr[p] = (int)(pk & smask);
  }
}

// ---------------- merged prep: x->bf16, gwhh cast, lw select, lbias, Bp fold ----
__global__ __launch_bounds__(256) void prep_all_k(
    const float* __restrict__ x, unsigned short* __restrict__ xb, int n4,
    const float* __restrict__ gwhh, const float* __restrict__ lwih,
    const float* __restrict__ lbih, const float* __restrict__ lbhh,
    const float* __restrict__ W, const float* __restrict__ gwih,
    unsigned short* __restrict__ gwhhb, unsigned short* __restrict__ lwb,
    float* __restrict__ lbias, unsigned short* __restrict__ Bpb) {
  int t = blockIdx.x * 256 + threadIdx.x;
  if (t < n4) {  // x conversion, 4 floats/thread
    float4 v = reinterpret_cast<const float4*>(x)[t];
    ushort4 o;
    o.x = f2bf(v.x); o.y = f2bf(v.y); o.z = f2bf(v.z); o.w = f2bf(v.w);
    reinterpret_cast<ushort4*>(xb)[t] = o;
    return;
  }
  t -= n4;
  if (t < 49152) { gwhhb[t] = f2bf(gwhh[t]); return; }
  t -= 49152;
  if (t < 49152) {  // select i,g,o rows of [512,128]
    int j = t >> 7, k = t & 127;
    int jm = j < 128 ? j : j + 128;
    lwb[t] = f2bf(lwih[(size_t)jm * 128 + k]);
    return;
  }
  t -= 49152;
  if (t < 384) {
    int jm = t < 128 ? t : t + 128;
    lbias[t] = lbih[jm] + lbhh[jm];
    return;
  }
  t -= 384;
  if (t < 49152) {  // Bp[j,k] = sum_c W[k,c]*gwih[j,c]
    int j = t >> 7, k = t & 127;
    const float4* wr = reinterpret_cast<const float4*>(W + (size_t)k * 128);
    const float4* gr = reinterpret_cast<const float4*>(gwih + (size_t)j * 128);
    float acc = 0.f;
#pragma unroll
    for (int c = 0; c < 32; ++c) {
      float4 a = wr[c], b = gr[c];
      acc += a.x * b.x + a.y * b.y + a.z * b.z + a.w * b.w;
    }
    Bpb[t] = f2bf(acc);
  }
}

// ---------------- gather (bf16 in, bf16 out) ----------------
__device__ __forceinline__ void acc8(float* acc, uint4 v) {
  acc[0] += bf2f((unsigned short)v.x);
  acc[1] += bf2f((unsigned short)(v.x >> 16));
  acc[2] += bf2f((unsigned short)v.y);
  acc[3] += bf2f((unsigned short)(v.y >> 16));
  acc[4] += bf2f((unsigned short)v.z);
  acc[5] += bf2f((unsigned short)(v.z >> 16));
  acc[6] += bf2f((unsigned short)v.w);
  acc[7] += bf2f((unsigned short)(v.w >> 16));
}

__global__ __launch_bounds__(256) void gather_b_k(const int* __restrict__ csr,
                                                  const int* __restrict__ rowstart,
                                                  const unsigned short* __restrict__ xb,
                                                  unsigned short* __restrict__ xaggb, int N) {
  int w = (int)(((long long)blockIdx.x * 256 + threadIdx.x) >> 6);
  if (w >= N) return;
  const int lane = threadIdx.x & 63;
  const int sub = lane >> 4, li = lane & 15;
  const int beg = rowstart[w], end = rowstart[w + 1];
  const uint4* x4 = reinterpret_cast<const uint4*>(xb);  // row = 16 uint4

  float acc[8] = {0.f, 0.f, 0.f, 0.f, 0.f, 0.f, 0.f, 0.f};

  int j = beg;
  for (; j + 16 <= end; j += 16) {
    int s0 = csr[j + sub];
    int s1 = csr[j + 4 + sub];
    int s2 = csr[j + 8 + sub];
    int s3 = csr[j + 12 + sub];
    uint4 v0 = x4[(size_t)s0 * 16 + li];
    uint4 v1 = x4[(size_t)s1 * 16 + li];
    uint4 v2 = x4[(size_t)s2 * 16 + li];
    uint4 v3 = x4[(size_t)s3 * 16 + li];
    acc8(acc, v0); acc8(acc, v1); acc8(acc, v2); acc8(acc, v3);
  }
  for (; j + 4 <= end; j += 4) {
    int s0 = csr[j + sub];
    uint4 v0 = x4[(size_t)s0 * 16 + li];
    acc8(acc, v0);
  }
  int rem = end - j;  // 0..3
  if (sub < rem) {
    int s0 = csr[j + sub];
    uint4 v0 = x4[(size_t)s0 * 16 + li];
    acc8(acc, v0);
  }

#pragma unroll
  for (int i = 0; i < 8; ++i) {
    acc[i] += __shfl_xor(acc[i], 16, 64);
    acc[i] += __shfl_xor(acc[i], 32, 64);
  }

  if (lane < 16) {
    float scale = 1.0f / fmaxf((float)(end - beg), 1.0f);
    uint4 o;
    o.x = (unsigned)f2bf(acc[0] * scale) | ((unsigned)f2bf(acc[1] * scale) << 16);
    o.y = (unsigned)f2bf(acc[2] * scale) | ((unsigned)f2bf(acc[3] * scale) << 16);
    o.z = (unsigned)f2bf(acc[4] * scale) | ((unsigned)f2bf(acc[5] * scale) << 16);
    o.w = (unsigned)f2bf(acc[6] * scale) | ((unsigned)f2bf(acc[7] * scale) << 16);
    reinterpret_cast<uint4*>(xaggb)[(size_t)w * 16 + li] = o;
  }
}

// ---------------- fused GRU (persistent row-tile loop) ----------------
// grid (4, G); block stages its 6-plane 32-col weight tile ONCE, then
// grid-strides over row-tiles. No barrier needed inside the loop.
__global__ __launch_bounds__(256) void gru_fused_k(
    const unsigned short* __restrict__ xaggb, const unsigned short* __restrict__ xb,
    const unsigned short* __restrict__ Bpb, const unsigned short* __restrict__ gwhhb,
    const float* __restrict__ gbih, const float* __restrict__ gbhh,
    unsigned short* __restrict__ hconv, int nrows) {
  __shared__ unsigned short Bsm[6][32][136];  // 52 KB -> 2 blocks/CU
  const int tid = threadIdx.x;
  const int w = tid >> 6, lane = tid & 63;
  const int q = lane >> 4, r = lane & 15;
  const int c0 = blockIdx.x * 32;

#pragma unroll
  for (int it = 0; it < 12; ++it) {
    int idx = it * 256 + tid;
    int p = idx >> 9;
    int rem = idx & 511;
    int col = rem >> 4, kq = rem & 15;
    const unsigned short* src =
        (p < 3) ? Bpb + ((size_t)(p * 128 + c0 + col)) * HD
                : gwhhb + ((size_t)((p - 3) * 128 + c0 + col)) * HD;
    uint4 v = *reinterpret_cast<const uint4*>(src + kq * 8);
    *reinterpret_cast<uint4*>(&Bsm[p][col][kq * 8]) = v;
  }
  __syncthreads();

  // bias per (cb,col) is loop-invariant
  float bir[2], biz[2], bin[2], bhr[2], bhz[2], bhn[2];
#pragma unroll
  for (int cb = 0; cb < 2; ++cb) {
    int col = c0 + cb * 16 + r;
    bir[cb] = gbih[col]; biz[cb] = gbih[col + 128]; bin[cb] = gbih[col + 256];
    bhr[cb] = gbhh[col]; bhz[cb] = gbhh[col + 128]; bhn[cb] = gbhh[col + 256];
  }

  const int ntiles = (nrows + 63) >> 6;
  for (int tile = blockIdx.y; tile < ntiles; tile += gridDim.y) {
    const int row0 = tile << 6;
    int arow = row0 + (w << 4) + r;
    int ar = arow < nrows ? arow : nrows - 1;
    const unsigned short* Aa = xaggb + (size_t)ar * HD + q * 8;
    const unsigned short* Ax = xb + (size_t)ar * HD + q * 8;

    f32x4 acc[6][2];
#pragma unroll
    for (int p = 0; p < 6; ++p)
#pragma unroll
      for (int cb = 0; cb < 2; ++cb) acc[p][cb] = (f32x4)0.f;

#pragma unroll
    for (int ks = 0; ks < 4; ++ks) {
      short8 a1 = *reinterpret_cast<const short8*>(Aa + ks * 32);
      short8 a2 = *reinterpret_cast<const short8*>(Ax + ks * 32);
#pragma unroll
      for (int p = 0; p < 6; ++p) {
        short8 af = (p < 3) ? a1 : a2;
#pragma unroll
        for (int cb = 0; cb < 2; ++cb) {
          short8 bf = *reinterpret_cast<const short8*>(&Bsm[p][cb * 16 + r][ks * 32 + q * 8]);
          acc[p][cb] = __builtin_amdgcn_mfma_f32_16x16x32_bf16(af, bf, acc[p][cb], 0, 0, 0);
        }
      }
    }

#pragma unroll
    for (int cb = 0; cb < 2; ++cb) {
      int col = c0 + cb * 16 + r;
#pragma unroll
      for (int reg = 0; reg < 4; ++reg) {
        int row = row0 + (w << 4) + q * 4 + reg;
        if (row < nrows) {
          float ir = acc[0][cb][reg] + bir[cb], iz = acc[1][cb][reg] + biz[cb];
          float inn = acc[2][cb][reg] + bin[cb];
          float hr = acc[3][cb][reg] + bhr[cb], hz = acc[4][cb][reg] + bhz[cb];
          float hn = acc[5][cb][reg] + bhn[cb];
          float rr = sigf(ir + hr), zz = sigf(iz + hz);
          float nn = tanhf(inn + rr * hn);
          float xv = bf2f(xb[(size_t)row * HD + col]);
          hconv[(size_t)row * HD + col] = f2bf((1.f - zz) * nn + zz * xv);
        }
      }
    }
  }
}

// ---------------- fused LSTM (persistent row-tile loop) ----------------
__global__ __launch_bounds__(256) void lstm_fused_k(
    const unsigned short* __restrict__ hconv, const unsigned short* __restrict__ lwb,
    const float* __restrict__ lbias, float* __restrict__ out, int nrows) {
  __shared__ unsigned short Bsm[3][64][136];  // 52 KB
  const int tid = threadIdx.x;
  const int w = tid >> 6, lane = tid & 63;
  const int q = lane >> 4, r = lane & 15;
  const int c0 = blockIdx.x * 64;

#pragma unroll
  for (int it = 0; it < 12; ++it) {
    int idx = it * 256 + tid;
    int p = idx >> 10, rem = idx & 1023;
    int col = rem >> 4, kq = rem & 15;
    uint4 v = *reinterpret_cast<const uint4*>(
        lwb + ((size_t)(p * 128 + c0 + col)) * HD + kq * 8);
    *reinterpret_cast<uint4*>(&Bsm[p][col][kq * 8]) = v;
  }
  __syncthreads();

  float bi[4], bg[4], bo[4];
#pragma unroll
  for (int cb = 0; cb < 4; ++cb) {
    int col = c0 + cb * 16 + r;
    bi[cb] = lbias[col]; bg[cb] = lbias[col + 128]; bo[cb] = lbias[col + 256];
  }

  const int ntiles = (nrows + 63) >> 6;
  for (int tile = blockIdx.y; tile < ntiles; tile += gridDim.y) {
    const int row0 = tile << 6;
    int arow = row0 + (w << 4) + r;
    int ar = arow < nrows ? arow : nrows - 1;
    const unsigned short* Ap = hconv + (size_t)ar * HD + q * 8;

    f32x4 acc[3][4];
#pragma unroll
    for (int p = 0; p < 3; ++p)
#pragma unroll
      for (int cb = 0; cb < 4; ++cb) acc[p][cb] = (f32x4)0.f;

#pragma unroll
    for (int ks = 0; ks < 4; ++ks) {
      short8 af = *reinterpret_cast<const short8*>(Ap + ks * 32);
#pragma unroll
      for (int p = 0; p < 3; ++p)
#pragma unroll
        for (int cb = 0; cb < 4; ++cb) {
          short8 bf = *reinterpret_cast<const short8*>(&Bsm[p][cb * 16 + r][ks * 32 + q * 8]);
          acc[p][cb] = __builtin_amdgcn_mfma_f32_16x16x32_bf16(af, bf, acc[p][cb], 0, 0, 0);
        }
    }

#pragma unroll
    for (int cb = 0; cb < 4; ++cb) {
      int col = c0 + cb * 16 + r;
#pragma unroll
      for (int reg = 0; reg < 4; ++reg) {
        int row = row0 + (w << 4) + q * 4 + reg;
        if (row < nrows) {
          float ig = acc[0][cb][reg] + bi[cb];
          float gg = acc[1][cb][reg] + bg[cb];
          float og = acc[2][cb][reg] + bo[cb];
          float cc = sigf(ig) * tanhf(gg);
          out[(size_t)row * HD + col] = fmaxf(sigf(og) * tanhf(cc), 0.f);
        }
      }
    }
  }
}

// ---------------- host ----------------

extern "C" void kernel_launch(void* const* d_in, const int* in_sizes, int n_in,
                              void* d_out, int out_size, void* d_ws, size_t ws_size,
                              hipStream_t stream) {
  const float* x = (const float*)d_in[0];
  const int* ei = (const int*)d_in[1];
  const float* W = (const float*)d_in[2];
  const float* gw_ih = (const float*)d_in[3];
  const float* gw_hh = (const float*)d_in[4];
  const float* gb_ih = (const float*)d_in[5];
  const float* gb_hh = (const float*)d_in[6];
  const float* lw_ih = (const float*)d_in[7];
  const float* lb_ih = (const float*)d_in[9];
  const float* lb_hh = (const float*)d_in[10];
  float* out = (float*)d_out;

  const int N = in_sizes[0] / HD;
  const int E = in_sizes[1] / 2;
  const size_t nH = (size_t)N * HD;

  int shift = 9;
  while (((N + (1 << shift) - 1) >> shift) > 256) ++shift;
  const int NB = (N + (1 << shift) - 1) >> shift;
  const int sbits = 32 - shift;

  const size_t N4p = (size_t)((N + 1 + 7) & ~7);  // rowstart: N+1
  const size_t E4 = (size_t)((E + 3) & ~3);
  const size_t BC = (size_t)NB * PB + 8;
  const int sc_total = NB * PB;
  const int sc_nblk = (sc_total + SCB - 1) / SCB;

  // ws layout: [rowstart][bcnt][bsums][csr][ebuf|xb][hconv][Bpb][gwhhb][lwb][lbias]
  char* p = (char*)d_ws;
  int* rowstart = (int*)p;  p += 4 * N4p;
  int* bcnt = (int*)p;      p += 4 * BC;
  int* bsums = (int*)p;     p += 4 * 64;
  int* csr = (int*)p;       p += 4 * E4;
  size_t sz_eb = 4 * E4, sz_xb = 2 * nH;
  unsigned* ebuf = (unsigned*)p;            // dead after bfill2_k
  unsigned short* xb = (unsigned short*)p;  // written by prep_all_k after
  p += (sz_eb > sz_xb ? sz_eb : sz_xb);
  unsigned short* hconv = (unsigned short*)p;  p += 2 * nH;
  unsigned short* Bpb = (unsigned short*)p;    p += 2 * 49152;
  unsigned short* gwhhb = (unsigned short*)p;  p += 2 * 49152;
  unsigned short* lwb = (unsigned short*)p;    p += 2 * 49152;
  float* lbias = (float*)p;                    p += 4 * 384;

  unsigned short* xaggb = (unsigned short*)d_out;  // consumed before out written

  dim3 blk(256);
  const int ntiles = (N + 63) / 64;

  // CSR build (bucketed)
  bcount_k<<<PB, blk, 0, stream>>>(ei, bcnt, E, N, shift, NB);
  scan1_k<<<sc_nblk, blk, 0, stream>>>(bcnt, bsums, sc_total);
  scan2_k<<<1, blk, 0, stream>>>(bsums, sc_nblk);
  scan3_k<<<sc_nblk, blk, 0, stream>>>(bcnt, bsums, sc_total, sc_nblk);
  bpart_k<<<PB, blk, 0, stream>>>(ei, bcnt, ebuf, E, N, shift, NB, sbits);
  bfill2_k<<<NB, blk, 0, stream>>>(ebuf, bcnt, rowstart, csr, N, shift, NB, sbits);

  // merged prep (xb overwrites ebuf - dead after bfill2)
  {
    long long tthreads = (long long)(nH / 4) + 49152 + 49152 + 384 + 49152;
    prep_all_k<<<(unsigned)((tthreads + 255) / 256), blk, 0, stream>>>(
        x, xb, (int)(nH / 4), gw_hh, lw_ih, lb_ih, lb_hh, W, gw_ih,
        gwhhb, lwb, lbias, Bpb);
  }

  // aggregation
  long long gthreads = (long long)N * 64;
  gather_b_k<<<(unsigned)((gthreads + 255) / 256), blk, 0, stream>>>(
      csr, rowstart, xb, xaggb, N);

  // hconv = GRU(xagg, x): persistent tiles, weights staged once per block
  {
    int G = ntiles < 128 ? ntiles : 128;  // 4*G = 512 blocks = 2/CU
    gru_fused_k<<<dim3(4, G), blk, 0, stream>>>(
        xaggb, xb, Bpb, gwhhb, gb_ih, gb_hh, hconv, N);
  }

  // out = LSTM(hconv): persistent tiles
  {
    int G = ntiles < 256 ? ntiles : 256;  // 2*G = 512 blocks = 2/CU
    lstm_fused_k<<<dim3(2, G), blk, 0, stream>>>(hconv, lwb, lbias, out, N);
  }
}

// Round 14
// 519.875 us; speedup vs baseline: 1.1252x; 1.1252x over previous
//
#include <hip/hip_runtime.h>
#include <math.h>

#define HD 128
#define PB 256   // partition blocks for bucketed CSR build
#define SCB 4096 // elements per block in multi-block scan

typedef __attribute__((ext_vector_type(8))) short short8;
typedef __attribute__((ext_vector_type(4))) float f32x4;

__device__ __forceinline__ float sigf(float v) { return 1.0f / (1.0f + __expf(-v)); }

__device__ __forceinline__ unsigned short f2bf(float f) {
  union { float f; unsigned u; } v; v.f = f;
  unsigned r = (v.u + 0x7fffu + ((v.u >> 16) & 1u)) >> 16;
  return (unsigned short)r;
}
__device__ __forceinline__ float bf2f(unsigned short b) {
  union { unsigned u; float f; } v; v.u = ((unsigned)b) << 16;
  return v.f;
}

// ---------------- CSR build ----------------

__global__ __launch_bounds__(256) void bcount_k(const int* __restrict__ ei,
                                                int* __restrict__ bcnt,
                                                int E, int N, int shift, int NB) {
  __shared__ int h[256];
  const int blk = blockIdx.x, tid = threadIdx.x;
  h[tid] = 0;
  __syncthreads();
  int per = (E + PB - 1) / PB;
  int lo = blk * per;
  int hi = (lo + per < E) ? lo + per : E;
  for (int e = lo + tid; e < hi; e += 256) {
    int d = ei[(size_t)E + e];
    if ((unsigned)d >= (unsigned)N) continue;
    atomicAdd(&h[d >> shift], 1);
  }
  __syncthreads();
  if (tid < NB) bcnt[tid * PB + blk] = h[tid];
}

__global__ __launch_bounds__(256) void scan1_k(const int* __restrict__ a,
                                               int* __restrict__ bsums, int total) {
  __shared__ int ts[256];
  int b = blockIdx.x, tid = threadIdx.x;
  int lo = b * SCB + tid * 16;
  int s = 0;
#pragma unroll
  for (int i = 0; i < 16; ++i) {
    int idx = lo + i;
    if (idx < total) s += a[idx];
  }
  ts[tid] = s;
  __syncthreads();
  for (int off = 128; off > 0; off >>= 1) {
    if (tid < off) ts[tid] += ts[tid + off];
    __syncthreads();
  }
  if (tid == 0) bsums[b] = ts[0];
}

__global__ __launch_bounds__(256) void scan2_k(int* __restrict__ bsums, int nb) {
  __shared__ int ts[256];
  int tid = threadIdx.x;
  int v = (tid < nb) ? bsums[tid] : 0;
  ts[tid] = v;
  __syncthreads();
  for (int off = 1; off < 256; off <<= 1) {
    int u = (tid >= off) ? ts[tid - off] : 0;
    __syncthreads();
    ts[tid] += u;
    __syncthreads();
  }
  if (tid < nb) bsums[tid] = ts[tid] - v;  // exclusive
}

__global__ __launch_bounds__(256) void scan3_k(int* __restrict__ a,
                                               const int* __restrict__ bsums,
                                               int total, int nblk) {
  __shared__ int ts[256];
  int b = blockIdx.x, tid = threadIdx.x;
  int lo = b * SCB + tid * 16;
  int pre[16];
  int s = 0;
#pragma unroll
  for (int i = 0; i < 16; ++i) {
    int idx = lo + i;
    int xv = (idx < total) ? a[idx] : 0;
    pre[i] = s;
    s += xv;
  }
  ts[tid] = s;
  __syncthreads();
  for (int off = 1; off < 256; off <<= 1) {
    int u = (tid >= off) ? ts[tid - off] : 0;
    __syncthreads();
    ts[tid] += u;
    __syncthreads();
  }
  int off0 = ts[tid] - s + bsums[b];
#pragma unroll
  for (int i = 0; i < 16; ++i) {
    int idx = lo + i;
    if (idx < total) a[idx] = off0 + pre[i];
  }
  if (b == nblk - 1 && tid == 255) a[total] = off0 + s;  // grand total
}

__global__ __launch_bounds__(256) void bpart_k(const int* __restrict__ ei,
                                               const int* __restrict__ bstart,
                                               unsigned* __restrict__ ebuf,
                                               int E, int N, int shift, int NB,
                                               int sbits) {
  __shared__ int cur[256];
  const int blk = blockIdx.x, tid = threadIdx.x;
  if (tid < NB) cur[tid] = bstart[tid * PB + blk];
  __syncthreads();
  int per = (E + PB - 1) / PB;
  int lo = blk * per;
  int hi = (lo + per < E) ? lo + per : E;
  const unsigned dmask = (1u << shift) - 1u;
  for (int e = lo + tid; e < hi; e += 256) {
    int s = ei[e];
    int d = ei[(size_t)E + e];
    if ((unsigned)s >= (unsigned)N || (unsigned)d >= (unsigned)N) continue;
    int p = atomicAdd(&cur[d >> shift], 1);
    ebuf[p] = (((unsigned)d & dmask) << sbits) | (unsigned)s;
  }
}

__global__ __launch_bounds__(256) void bfill2_k(const unsigned* __restrict__ ebuf,
                                                const int* __restrict__ bstart,
                                                int* __restrict__ rowstart,
                                                int* __restrict__ csr,
                                                int N, int shift, int NB, int sbits) {
  __shared__ int cnt[2048];
  __shared__ int tsum[256];
  const int b = blockIdx.x, tid = threadIdx.x;
  const int d0 = b << shift;
  int dmax = d0 + (1 << shift);
  if (dmax > N) dmax = N;
  const int nd = dmax - d0;
  const unsigned smask = (1u << sbits) - 1u;
  for (int i = tid; i < nd; i += 256) cnt[i] = 0;
  __syncthreads();
  const int base = bstart[b * PB];
  const int end = bstart[(b + 1) * PB];  // b=NB-1 -> bstart[NB*PB] = grand total
  for (int idx = base + tid; idx < end; idx += 256)
    atomicAdd(&cnt[ebuf[idx] >> sbits], 1);
  __syncthreads();
  const int C = (nd + 255) / 256;  // <= 8
  int lo = tid * C;
  int hi = (lo + C < nd) ? lo + C : nd;
  int loc[8];
  int s = 0;
  for (int i = lo; i < hi; ++i) {
    loc[i - lo] = cnt[i];
    s += cnt[i];
  }
  tsum[tid] = s;
  __syncthreads();
  for (int off = 1; off < 256; off <<= 1) {
    int u = (tid >= off) ? tsum[tid - off] : 0;
    __syncthreads();
    tsum[tid] += u;
    __syncthreads();
  }
  int run = tsum[tid] - s + base;
  for (int i = lo; i < hi; ++i) {
    rowstart[d0 + i] = run;
    cnt[i] = run;  // becomes the cursor
    run += loc[i - lo];
  }
  if (b == NB - 1 && tid == 255) rowstart[N] = end;
  __syncthreads();
  for (int idx = base + tid; idx < end; idx += 256) {
    unsigned pk = ebuf[idx];
    int p = atomicAdd(&cnt[pk >> sbits], 1);
    csr[p] = (int)(pk & smask);
  }
}

// ---------------- merged prep: x->bf16, gwhh cast, lw select, lbias, Bp fold ----
__global__ __launch_bounds__(256) void prep_all_k(
    const float* __restrict__ x, unsigned short* __restrict__ xb, int n4,
    const float* __restrict__ gwhh, const float* __restrict__ lwih,
    const float* __restrict__ lbih, const float* __restrict__ lbhh,
    const float* __restrict__ W, const float* __restrict__ gwih,
    unsigned short* __restrict__ gwhhb, unsigned short* __restrict__ lwb,
    float* __restrict__ lbias, unsigned short* __restrict__ Bpb) {
  int t = blockIdx.x * 256 + threadIdx.x;
  if (t < n4) {  // x conversion, 4 floats/thread
    float4 v = reinterpret_cast<const float4*>(x)[t];
    ushort4 o;
    o.x = f2bf(v.x); o.y = f2bf(v.y); o.z = f2bf(v.z); o.w = f2bf(v.w);
    reinterpret_cast<ushort4*>(xb)[t] = o;
    return;
  }
  t -= n4;
  if (t < 49152) { gwhhb[t] = f2bf(gwhh[t]); return; }
  t -= 49152;
  if (t < 49152) {  // select i,g,o rows of [512,128]
    int j = t >> 7, k = t & 127;
    int jm = j < 128 ? j : j + 128;
    lwb[t] = f2bf(lwih[(size_t)jm * 128 + k]);
    return;
  }
  t -= 49152;
  if (t < 384) {
    int jm = t < 128 ? t : t + 128;
    lbias[t] = lbih[jm] + lbhh[jm];
    return;
  }
  t -= 384;
  if (t < 49152) {  // Bp[j,k] = sum_c W[k,c]*gwih[j,c]
    int j = t >> 7, k = t & 127;
    const float4* wr = reinterpret_cast<const float4*>(W + (size_t)k * 128);
    const float4* gr = reinterpret_cast<const float4*>(gwih + (size_t)j * 128);
    float acc = 0.f;
#pragma unroll
    for (int c = 0; c < 32; ++c) {
      float4 a = wr[c], b = gr[c];
      acc += a.x * b.x + a.y * b.y + a.z * b.z + a.w * b.w;
    }
    Bpb[t] = f2bf(acc);
  }
}

// ---------------- gather (bf16 in, bf16 out) ----------------
__device__ __forceinline__ void acc8(float* acc, uint4 v) {
  acc[0] += bf2f((unsigned short)v.x);
  acc[1] += bf2f((unsigned short)(v.x >> 16));
  acc[2] += bf2f((unsigned short)v.y);
  acc[3] += bf2f((unsigned short)(v.y >> 16));
  acc[4] += bf2f((unsigned short)v.z);
  acc[5] += bf2f((unsigned short)(v.z >> 16));
  acc[6] += bf2f((unsigned short)v.w);
  acc[7] += bf2f((unsigned short)(v.w >> 16));
}

__global__ __launch_bounds__(256) void gather_b_k(const int* __restrict__ csr,
                                                  const int* __restrict__ rowstart,
                                                  const unsigned short* __restrict__ xb,
                                                  unsigned short* __restrict__ xaggb, int N) {
  int w = (int)(((long long)blockIdx.x * 256 + threadIdx.x) >> 6);
  if (w >= N) return;
  const int lane = threadIdx.x & 63;
  const int sub = lane >> 4, li = lane & 15;
  const int beg = rowstart[w], end = rowstart[w + 1];
  const uint4* x4 = reinterpret_cast<const uint4*>(xb);  // row = 16 uint4

  float acc[8] = {0.f, 0.f, 0.f, 0.f, 0.f, 0.f, 0.f, 0.f};

  int j = beg;
  for (; j + 16 <= end; j += 16) {
    int s0 = csr[j + sub];
    int s1 = csr[j + 4 + sub];
    int s2 = csr[j + 8 + sub];
    int s3 = csr[j + 12 + sub];
    uint4 v0 = x4[(size_t)s0 * 16 + li];
    uint4 v1 = x4[(size_t)s1 * 16 + li];
    uint4 v2 = x4[(size_t)s2 * 16 + li];
    uint4 v3 = x4[(size_t)s3 * 16 + li];
    acc8(acc, v0); acc8(acc, v1); acc8(acc, v2); acc8(acc, v3);
  }
  for (; j + 4 <= end; j += 4) {
    int s0 = csr[j + sub];
    uint4 v0 = x4[(size_t)s0 * 16 + li];
    acc8(acc, v0);
  }
  int rem = end - j;  // 0..3
  if (sub < rem) {
    int s0 = csr[j + sub];
    uint4 v0 = x4[(size_t)s0 * 16 + li];
    acc8(acc, v0);
  }

#pragma unroll
  for (int i = 0; i < 8; ++i) {
    acc[i] += __shfl_xor(acc[i], 16, 64);
    acc[i] += __shfl_xor(acc[i], 32, 64);
  }

  if (lane < 16) {
    float scale = 1.0f / fmaxf((float)(end - beg), 1.0f);
    uint4 o;
    o.x = (unsigned)f2bf(acc[0] * scale) | ((unsigned)f2bf(acc[1] * scale) << 16);
    o.y = (unsigned)f2bf(acc[2] * scale) | ((unsigned)f2bf(acc[3] * scale) << 16);
    o.z = (unsigned)f2bf(acc[4] * scale) | ((unsigned)f2bf(acc[5] * scale) << 16);
    o.w = (unsigned)f2bf(acc[6] * scale) | ((unsigned)f2bf(acc[7] * scale) << 16);
    reinterpret_cast<uint4*>(xaggb)[(size_t)w * 16 + li] = o;
  }
}

// ---------------- fused GRU (round-12 grid: one 64-row tile per block) ----------
__global__ __launch_bounds__(256) void gru_fused_k(
    const unsigned short* __restrict__ xaggb, const unsigned short* __restrict__ xb,
    const unsigned short* __restrict__ Bpb, const unsigned short* __restrict__ gwhhb,
    const float* __restrict__ gbih, const float* __restrict__ gbhh,
    unsigned short* __restrict__ hconv, int nrows) {
  __shared__ unsigned short Bsm[6][32][136];
  const int tid = threadIdx.x;
  const int w = tid >> 6, lane = tid & 63;
  const int q = lane >> 4, r = lane & 15;
  const int row0 = blockIdx.y * 64;
  const int c0 = blockIdx.x * 32;

#pragma unroll
  for (int it = 0; it < 12; ++it) {
    int idx = it * 256 + tid;
    int p = idx >> 9;
    int rem = idx & 511;
    int col = rem >> 4, kq = rem & 15;
    const unsigned short* src =
        (p < 3) ? Bpb + ((size_t)(p * 128 + c0 + col)) * HD
                : gwhhb + ((size_t)((p - 3) * 128 + c0 + col)) * HD;
    uint4 v = *reinterpret_cast<const uint4*>(src + kq * 8);
    *reinterpret_cast<uint4*>(&Bsm[p][col][kq * 8]) = v;
  }
  __syncthreads();

  int arow = row0 + (w << 4) + r;
  int ar = arow < nrows ? arow : nrows - 1;
  const unsigned short* Aa = xaggb + (size_t)ar * HD + q * 8;
  const unsigned short* Ax = xb + (size_t)ar * HD + q * 8;

  f32x4 acc[6][2];
#pragma unroll
  for (int p = 0; p < 6; ++p)
#pragma unroll
    for (int cb = 0; cb < 2; ++cb) acc[p][cb] = (f32x4)0.f;

#pragma unroll
  for (int ks = 0; ks < 4; ++ks) {
    short8 a1 = *reinterpret_cast<const short8*>(Aa + ks * 32);
    short8 a2 = *reinterpret_cast<const short8*>(Ax + ks * 32);
#pragma unroll
    for (int p = 0; p < 6; ++p) {
      short8 af = (p < 3) ? a1 : a2;
#pragma unroll
      for (int cb = 0; cb < 2; ++cb) {
        short8 bf = *reinterpret_cast<const short8*>(&Bsm[p][cb * 16 + r][ks * 32 + q * 8]);
        acc[p][cb] = __builtin_amdgcn_mfma_f32_16x16x32_bf16(af, bf, acc[p][cb], 0, 0, 0);
      }
    }
  }

#pragma unroll
  for (int cb = 0; cb < 2; ++cb) {
    int col = c0 + cb * 16 + r;
    float bir = gbih[col], biz = gbih[col + 128], bin = gbih[col + 256];
    float bhr = gbhh[col], bhz = gbhh[col + 128], bhn = gbhh[col + 256];
#pragma unroll
    for (int reg = 0; reg < 4; ++reg) {
      int row = row0 + (w << 4) + q * 4 + reg;
      if (row < nrows) {
        float ir = acc[0][cb][reg] + bir, iz = acc[1][cb][reg] + biz;
        float inn = acc[2][cb][reg] + bin;
        float hr = acc[3][cb][reg] + bhr, hz = acc[4][cb][reg] + bhz;
        float hn = acc[5][cb][reg] + bhn;
        float rr = sigf(ir + hr), zz = sigf(iz + hz);
        float nn = tanhf(inn + rr * hn);
        float xv = bf2f(xb[(size_t)row * HD + col]);
        hconv[(size_t)row * HD + col] = f2bf((1.f - zz) * nn + zz * xv);
      }
    }
  }
}

// ---------------- fused LSTM (round-12 grid) ----------------
__global__ __launch_bounds__(256) void lstm_fused_k(
    const unsigned short* __restrict__ hconv, const unsigned short* __restrict__ lwb,
    const float* __restrict__ lbias, float* __restrict__ out, int nrows) {
  __shared__ unsigned short Bsm[3][64][136];
  const int tid = threadIdx.x;
  const int w = tid >> 6, lane = tid & 63;
  const int q = lane >> 4, r = lane & 15;
  const int row0 = blockIdx.y * 64;
  const int c0 = blockIdx.x * 64;

#pragma unroll
  for (int it = 0; it < 12; ++it) {
    int idx = it * 256 + tid;
    int p = idx >> 10, rem = idx & 1023;
    int col = rem >> 4, kq = rem & 15;
    uint4 v = *reinterpret_cast<const uint4*>(
        lwb + ((size_t)(p * 128 + c0 + col)) * HD + kq * 8);
    *reinterpret_cast<uint4*>(&Bsm[p][col][kq * 8]) = v;
  }
  __syncthreads();

  int arow = row0 + (w << 4) + r;
  int ar = arow < nrows ? arow : nrows - 1;
  const unsigned short* Ap = hconv + (size_t)ar * HD + q * 8;

  f32x4 acc[3][4];
#pragma unroll
  for (int p = 0; p < 3; ++p)
#pragma unroll
    for (int cb = 0; cb < 4; ++cb) acc[p][cb] = (f32x4)0.f;

#pragma unroll
  for (int ks = 0; ks < 4; ++ks) {
    short8 af = *reinterpret_cast<const short8*>(Ap + ks * 32);
#pragma unroll
    for (int p = 0; p < 3; ++p)
#pragma unroll
      for (int cb = 0; cb < 4; ++cb) {
        short8 bf = *reinterpret_cast<const short8*>(&Bsm[p][cb * 16 + r][ks * 32 + q * 8]);
        acc[p][cb] = __builtin_amdgcn_mfma_f32_16x16x32_bf16(af, bf, acc[p][cb], 0, 0, 0);
      }
  }

#pragma unroll
  for (int cb = 0; cb < 4; ++cb) {
    int col = c0 + cb * 16 + r;
    float bi = lbias[col], bg = lbias[col + 128], bo = lbias[col + 256];
#pragma unroll
    for (int reg = 0; reg < 4; ++reg) {
      int row = row0 + (w << 4) + q * 4 + reg;
      if (row < nrows) {
        float ig = acc[0][cb][reg] + bi;
        float gg = acc[1][cb][reg] + bg;
        float og = acc[2][cb][reg] + bo;
        float cc = sigf(ig) * tanhf(gg);
        out[(size_t)row * HD + col] = fmaxf(sigf(og) * tanhf(cc), 0.f);
      }
    }
  }
}

// ---------------- host ----------------

extern "C" void kernel_launch(void* const* d_in, const int* in_sizes, int n_in,
                              void* d_out, int out_size, void* d_ws, size_t ws_size,
                              hipStream_t stream) {
  const float* x = (const float*)d_in[0];
  const int* ei = (const int*)d_in[1];
  const float* W = (const float*)d_in[2];
  const float* gw_ih = (const float*)d_in[3];
  const float* gw_hh = (const float*)d_in[4];
  const float* gb_ih = (const float*)d_in[5];
  const float* gb_hh = (const float*)d_in[6];
  const float* lw_ih = (const float*)d_in[7];
  const float* lb_ih = (const float*)d_in[9];
  const float* lb_hh = (const float*)d_in[10];
  float* out = (float*)d_out;

  const int N = in_sizes[0] / HD;
  const int E = in_sizes[1] / 2;
  const size_t nH = (size_t)N * HD;

  int shift = 9;
  while (((N + (1 << shift) - 1) >> shift) > 256) ++shift;
  const int NB = (N + (1 << shift) - 1) >> shift;
  const int sbits = 32 - shift;

  const size_t N4p = (size_t)((N + 1 + 7) & ~7);  // rowstart: N+1
  const size_t E4 = (size_t)((E + 3) & ~3);
  const size_t BC = (size_t)NB * PB + 8;
  const int sc_total = NB * PB;
  const int sc_nblk = (sc_total + SCB - 1) / SCB;

  // ws layout: [rowstart][bcnt][bsums][csr][ebuf|xb][hconv][Bpb][gwhhb][lwb][lbias]
  char* p = (char*)d_ws;
  int* rowstart = (int*)p;  p += 4 * N4p;
  int* bcnt = (int*)p;      p += 4 * BC;
  int* bsums = (int*)p;     p += 4 * 64;
  int* csr = (int*)p;       p += 4 * E4;
  size_t sz_eb = 4 * E4, sz_xb = 2 * nH;
  unsigned* ebuf = (unsigned*)p;            // dead after bfill2_k
  unsigned short* xb = (unsigned short*)p;  // written by prep_all_k after
  p += (sz_eb > sz_xb ? sz_eb : sz_xb);
  unsigned short* hconv = (unsigned short*)p;  p += 2 * nH;
  unsigned short* Bpb = (unsigned short*)p;    p += 2 * 49152;
  unsigned short* gwhhb = (unsigned short*)p;  p += 2 * 49152;
  unsigned short* lwb = (unsigned short*)p;    p += 2 * 49152;
  float* lbias = (float*)p;                    p += 4 * 384;

  unsigned short* xaggb = (unsigned short*)d_out;  // consumed before out written

  dim3 blk(256);
  unsigned rb = (unsigned)((N + 63) / 64);

  // CSR build (bucketed)
  bcount_k<<<PB, blk, 0, stream>>>(ei, bcnt, E, N, shift, NB);
  scan1_k<<<sc_nblk, blk, 0, stream>>>(bcnt, bsums, sc_total);
  scan2_k<<<1, blk, 0, stream>>>(bsums, sc_nblk);
  scan3_k<<<sc_nblk, blk, 0, stream>>>(bcnt, bsums, sc_total, sc_nblk);
  bpart_k<<<PB, blk, 0, stream>>>(ei, bcnt, ebuf, E, N, shift, NB, sbits);
  bfill2_k<<<NB, blk, 0, stream>>>(ebuf, bcnt, rowstart, csr, N, shift, NB, sbits);

  // merged prep (xb overwrites ebuf - dead after bfill2)
  {
    long long tthreads = (long long)(nH / 4) + 49152 + 49152 + 384 + 49152;
    prep_all_k<<<(unsigned)((tthreads + 255) / 256), blk, 0, stream>>>(
        x, xb, (int)(nH / 4), gw_hh, lw_ih, lb_ih, lb_hh, W, gw_ih,
        gwhhb, lwb, lbias, Bpb);
  }

  // aggregation
  long long gthreads = (long long)N * 64;
  gather_b_k<<<(unsigned)((gthreads + 255) / 256), blk, 0, stream>>>(
      csr, rowstart, xb, xaggb, N);

  // hconv = GRU(xagg, x) with W folded into the input-gate weight
  gru_fused_k<<<dim3(4, rb), blk, 0, stream>>>(
      xaggb, xb, Bpb, gwhhb, gb_ih, gb_hh, hconv, N);

  // out = LSTM(hconv)
  lstm_fused_k<<<dim3(2, rb), blk, 0, stream>>>(hconv, lwb, lbias, out, N);
}